// Round 12
// baseline (153.837 us; speedup 1.0000x reference)
//
#include <hip/hip_runtime.h>

#define NHEAD 32
#define LSEQ  2048
#define DIM   64
#define QBLK  64
#define KBLK  64
#define NTILE (LSEQ / KBLK)

typedef float  f32x4  __attribute__((ext_vector_type(4)));
typedef __bf16 bf16x8 __attribute__((ext_vector_type(8)));
typedef unsigned short u16;

__device__ __forceinline__ u16 f2bf(float f) {
    return __builtin_bit_cast(u16, (__bf16)f);   // HW RNE convert
}
__device__ __forceinline__ void st4bf(u16* p, float4 v) {
    union { u16 h[4]; uint2 q; } pk;
    pk.h[0] = f2bf(v.x); pk.h[1] = f2bf(v.y);
    pk.h[2] = f2bf(v.z); pk.h[3] = f2bf(v.w);
    *(uint2*)p = pk.q;
}
__device__ __forceinline__ bf16x8 comb64(const u16* a, const u16* b) {
    union { uint2 q[2]; bf16x8 v; } u;
    u.q[0] = *(const uint2*)a;
    u.q[1] = *(const uint2*)b;
    return u.v;
}

// async global->LDS, 16B per lane (HW: wave-uniform LDS base + lane*16)
__device__ __forceinline__ void gl_lds16(const u16* g, u16* l) {
    __builtin_amdgcn_global_load_lds(
        (const __attribute__((address_space(1))) void*)g,
        (__attribute__((address_space(3))) void*)l, 16, 0, 0);
}

// drain own async stages + barrier (no lgkm drain: zero ds_writes in-loop)
#define TILE_SYNC() asm volatile("s_waitcnt vmcnt(0)\n\ts_barrier" ::: "memory")

// 0.125 (1/sqrt(64)) * log2(e): softmax computed in exp2 domain
#define QSCALE 0.18033688011112042f
#define RESCALE_THR 8.0f

// ============================================================================
// Pre-pass: K -> bf16 tiles, V -> V^T bf16 tiles (gload_lds-linear + XOR-
// swizzled layout), PLUS the mask^2 loss term. (r7 version: fp32 mask kept —
// r11 measured bf16-mask conversion as +3us prepack for zero attn gain)
// ============================================================================
__global__ void prepack_kernel(const float* __restrict__ K,
                               const float* __restrict__ V,
                               const float* __restrict__ Msk,
                               u16* __restrict__ wsK, u16* __restrict__ wsV,
                               float* __restrict__ loss)
{
    __shared__ float sv[64][65];
    __shared__ float red2[4];
    const int b = blockIdx.x;          // head*NTILE + kb
    const int head = b >> 5, kb = b & 31;
    const int t = threadIdx.x;
    const size_t hoff = (size_t)head * LSEQ * DIM;
    const float* Kg = K + hoff + (size_t)(kb * KBLK) * DIM;
    const float* Vg = V + hoff + (size_t)(kb * KBLK) * DIM;
    u16* outK = wsK + (size_t)b * 4096;
    u16* outV = wsV + (size_t)b * 4096;

#pragma unroll
    for (int i = 0; i < 16; ++i) {
        const int e = t + 256 * i;
        sv[e >> 6][e & 63] = Vg[e];
    }
#pragma unroll
    for (int i = 0; i < 2; ++i) {
        const int c = t + 256 * i;
        const int r = c >> 3, q = c & 7;
        const int d0 = 8 * (q ^ (r & 7));
        float4 a  = *(const float4*)(Kg + r * DIM + d0);
        float4 bb = *(const float4*)(Kg + r * DIM + d0 + 4);
        union { u16 h[8]; uint4 u; } pk;
        pk.h[0]=f2bf(a.x);  pk.h[1]=f2bf(a.y);  pk.h[2]=f2bf(a.z);  pk.h[3]=f2bf(a.w);
        pk.h[4]=f2bf(bb.x); pk.h[5]=f2bf(bb.y); pk.h[6]=f2bf(bb.z); pk.h[7]=f2bf(bb.w);
        *(uint4*)(outK + c * 8) = pk.u;
    }
    __syncthreads();
#pragma unroll
    for (int i = 0; i < 2; ++i) {
        const int c = t + 256 * i;
        const int d = c >> 3, q = c & 7;
        const int cl = q ^ (d & 7);
        const int mp = cl >> 2, lq = cl & 3;
        union { u16 h[8]; uint4 u; } pk;
#pragma unroll
        for (int s = 0; s < 2; ++s) {
            const int k0 = 4 * (8 * mp + 4 * s + lq);
#pragma unroll
            for (int j = 0; j < 4; ++j)
                pk.h[4 * s + j] = f2bf(sv[k0 + j][d]);
        }
        *(uint4*)(outV + c * 8) = pk.u;
    }

    float s = 0.f;
    const float4* mq = (const float4*)(Msk + (size_t)b * 4096);
#pragma unroll
    for (int i = 0; i < 4; ++i) {
        float4 v = mq[t + 256 * i];
        s += v.x * v.x + v.y * v.y + v.z * v.z + v.w * v.w;
    }
#pragma unroll
    for (int off = 1; off <= 32; off <<= 1) s += __shfl_xor(s, off);
    if ((t & 63) == 0) red2[t >> 6] = s;
    __syncthreads();
    if (t == 0)
        atomicAdd(loss, 32.0f * (red2[0] + red2[1] + red2[2] + red2[3]));
}

// ----------------------------------------------------------------------------
// Textual macros (rule #20: no lambda/pointer boundaries for register state).
// ----------------------------------------------------------------------------
#define STAGE(tile, kbuf, vbuf)                                                \
    {                                                                          \
        const u16* gk = srcK + (size_t)(tile) * 4096;                          \
        const u16* gv = srcV + (size_t)(tile) * 4096;                          \
        gl_lds16(gk,        &lds_k[kbuf][t * 8]);                              \
        gl_lds16(gk + 2048, &lds_k[kbuf][t * 8 + 2048]);                       \
        gl_lds16(gv,        &lds_v[vbuf][t * 8]);                              \
        gl_lds16(gv + 2048, &lds_v[vbuf][t * 8 + 2048]);                       \
    }

// mask double-buffer load into named set M (mA or mB); ALWAYS issued before
// STAGE in a period and consumed one full period later -> its vmcnt wait is
// long-satisfied, and (unlike r7) SMF never FIFO-drains the in-flight stage.
#define LDMASK(kb_, M)                                                         \
    {                                                                          \
        const float* mp_ = Msk + (size_t)qg * LSEQ + (kb_) * KBLK + 4 * lq;    \
        M##0 = *(const f32x4*)(mp_);                                           \
        M##1 = *(const f32x4*)(mp_ + 16);                                      \
        M##2 = *(const f32x4*)(mp_ + 32);                                      \
        M##3 = *(const f32x4*)(mp_ + 48);                                      \
    }

#define QK1(kb_, mm, Sdst)                                                     \
    {                                                                          \
        const u16* kro = (kb_) + (16 * (mm) + lr) * 64;                        \
        bf16x8 kf0 = *(const bf16x8*)(kro + ((lq ^ x7) << 3));                 \
        bf16x8 kf1 = *(const bf16x8*)(kro + (((lq + 4) ^ x7) << 3));           \
        f32x4 z = (f32x4){0.f, 0.f, 0.f, 0.f};                                 \
        z = __builtin_amdgcn_mfma_f32_16x16x32_bf16(kf0, qf[0], z, 0, 0, 0);   \
        z = __builtin_amdgcn_mfma_f32_16x16x32_bf16(kf1, qf[1], z, 0, 0, 0);   \
        Sdst = z;                                                              \
    }

// QK for tile -> 4 named S regs (independent of the SMF/PV chain below it)
#define QK(kbuf, SD0, SD1, SD2, SD3)                                           \
    {                                                                          \
        const u16* kb_ = &lds_k[kbuf][0];                                      \
        __builtin_amdgcn_s_setprio(1);                                         \
        QK1(kb_, 0, SD0) QK1(kb_, 1, SD1) QK1(kb_, 2, SD2) QK1(kb_, 3, SD3)    \
        __builtin_amdgcn_s_setprio(0);                                         \
    }

#define SMPART(Sm, Mm, base)                                                   \
    {                                                                          \
        _Pragma("unroll")                                                      \
        for (int r = 0; r < 4; ++r) {                                          \
            float pe = __builtin_amdgcn_exp2f(Sm[r] - mrun);                   \
            psum += pe;                                                        \
            pp2  += pe * pe;                                                   \
            ppm  += pe * Mm[r];                                                \
            pb[(base) + r] = f2bf(pe);                                         \
        }                                                                      \
    }

// softmax-finish of the PREVIOUS tile (VALU only) -> pf0/pf1 + running state;
// mask set M was loaded one full period ago (double-buffered)
#define SMF(SS0, SS1, SS2, SS3, M)                                             \
    {                                                                          \
        float tm = fmaxf(fmaxf(fmaxf(SS0[0], SS0[1]), fmaxf(SS0[2], SS0[3])),  \
                         fmaxf(fmaxf(SS1[0], SS1[1]), fmaxf(SS1[2], SS1[3]))); \
        tm = fmaxf(tm, fmaxf(fmaxf(fmaxf(SS2[0], SS2[1]), fmaxf(SS2[2], SS2[3])), \
                             fmaxf(fmaxf(SS3[0], SS3[1]), fmaxf(SS3[2], SS3[3])))); \
        if (!__all(tm - mrun <= RESCALE_THR)) {                                \
            tm = fmaxf(tm, __shfl_xor(tm, 16));                                \
            tm = fmaxf(tm, __shfl_xor(tm, 32));                                \
            const float mn = fmaxf(mrun, tm);                                  \
            const float al = __builtin_amdgcn_exp2f(mrun - mn);                \
            mrun = mn;                                                         \
            lrun *= al; la2 *= al * al; lam *= al;                             \
            _Pragma("unroll")                                                  \
            for (int dt = 0; dt < 4; ++dt) acc[dt] *= al;                      \
        }                                                                      \
        float psum = 0.f, pp2 = 0.f, ppm = 0.f;                                \
        u16 pb[16];                                                            \
        SMPART(SS0, M##0, 0) SMPART(SS1, M##1, 4)                              \
        SMPART(SS2, M##2, 8) SMPART(SS3, M##3, 12)                             \
        lrun += psum; la2 += pp2; lam += ppm;                                  \
        {                                                                      \
            union { u16 h[8]; bf16x8 v; } u;                                   \
            u.h[0] = pb[0]; u.h[1] = pb[1]; u.h[2] = pb[2]; u.h[3] = pb[3];    \
            u.h[4] = pb[4]; u.h[5] = pb[5]; u.h[6] = pb[6]; u.h[7] = pb[7];    \
            pf0 = u.v;                                                         \
        }                                                                      \
        {                                                                      \
            union { u16 h[8]; bf16x8 v; } u;                                   \
            u.h[0] = pb[8];  u.h[1] = pb[9];  u.h[2] = pb[10]; u.h[3] = pb[11];\
            u.h[4] = pb[12]; u.h[5] = pb[13]; u.h[6] = pb[14]; u.h[7] = pb[15];\
            pf1 = u.v;                                                         \
        }                                                                      \
    }

// PV accumulate of the PREVIOUS tile from V buffer vidx (uses pf0/pf1)
#define PV(vidx)                                                               \
    {                                                                          \
        const u16* vb_ = &lds_v[vidx][0];                                      \
        __builtin_amdgcn_s_setprio(1);                                         \
        _Pragma("unroll")                                                      \
        for (int dt = 0; dt < 4; ++dt) {                                       \
            const u16* vro = vb_ + (16 * dt + lr) * 64;                        \
            bf16x8 vfa = *(const bf16x8*)(vro + ((lq ^ x7) << 3));             \
            bf16x8 vfb = *(const bf16x8*)(vro + (((4 + lq) ^ x7) << 3));       \
            acc[dt] = __builtin_amdgcn_mfma_f32_16x16x32_bf16(vfa, pf0, acc[dt], 0, 0, 0); \
            acc[dt] = __builtin_amdgcn_mfma_f32_16x16x32_bf16(vfb, pf1, acc[dt], 0, 0, 0); \
        }                                                                      \
        __builtin_amdgcn_s_setprio(0);                                         \
    }

#define ROT3(x) x = ((x) == 2) ? 0 : ((x) + 1);

// ============================================================================
// Main fused kernel: r7 two-tile software pipeline (best measured config)
// + true mask register double-buffer (mask(t) issued a full period early,
// BEFORE the stage, so SMF's mask wait never FIFO-drains in-flight stages).
// ============================================================================
__launch_bounds__(256, 4)
__global__ void attn_fused_kernel(const float* __restrict__ Q,
                                  const u16* __restrict__ wsK,
                                  const u16* __restrict__ wsV,
                                  const float* __restrict__ Msk,
                                  float* __restrict__ out,
                                  float* __restrict__ loss)
{
    __shared__ __align__(16) u16 lds_k[2][4096];   // 8KB K tile image x2
    __shared__ __align__(16) u16 lds_v[3][4096];   // 8KB V^T tile image x3

    const int t  = threadIdx.x;
    // bijective XCD-chunked swizzle: 1024 blocks, 8 XCDs, 128-block chunks
    const int wg   = ((int)blockIdx.x & 7) * 128 + ((int)blockIdx.x >> 3);
    const int head = wg >> 5;
    const int qb   = wg & 31;
    const int qbase = qb * QBLK;
    const int w  = t >> 6;
    const int l  = t & 63;
    const int lr = l & 15;
    const int lq = l >> 4;
    const int x7 = lr & 7;

    const size_t hoff = (size_t)head * LSEQ * DIM;
    const int qg = qbase + 16 * w + lr;

    // ---- Q fragments, scale folded in (slots c = 32s + 8lq + j) ----
    bf16x8 qf[2];
#pragma unroll
    for (int s = 0; s < 2; ++s) {
        const float* src = Q + hoff + (size_t)qg * DIM + 32 * s + 8 * lq;
        float4 a = *(const float4*)(src);
        float4 b = *(const float4*)(src + 4);
        union { u16 h[8]; bf16x8 v; } u;
        u.h[0] = f2bf(a.x * QSCALE); u.h[1] = f2bf(a.y * QSCALE);
        u.h[2] = f2bf(a.z * QSCALE); u.h[3] = f2bf(a.w * QSCALE);
        u.h[4] = f2bf(b.x * QSCALE); u.h[5] = f2bf(b.y * QSCALE);
        u.h[6] = f2bf(b.z * QSCALE); u.h[7] = f2bf(b.w * QSCALE);
        qf[s] = u.v;
    }

    f32x4 acc[4];
#pragma unroll
    for (int dt = 0; dt < 4; ++dt) acc[dt] = (f32x4){0.f, 0.f, 0.f, 0.f};
    float mrun = -1e30f, lrun = 0.f, la2 = 0.f, lam = 0.f;

    const u16* srcK = wsK + (size_t)(head * NTILE) * 4096 + t * 8;
    const u16* srcV = wsV + (size_t)(head * NTILE) * 4096 + t * 8;

    // pipeline register state: named, spill-proof
    f32x4 S_a0, S_a1, S_a2, S_a3, S_b0, S_b1, S_b2, S_b3;
    f32x4 mA0, mA1, mA2, mA3, mB0, mB1, mB2, mB3;
    bf16x8 pf0, pf1;

    // ---- prologue ----
    STAGE(0, 0, 0);
    TILE_SYNC();
    LDMASK(0, mA);                       // mask(0), before STAGE(1)
    STAGE(1, 1, 1);
    QK(0, S_a0, S_a1, S_a2, S_a3);       // tile 0 scores -> S_a
    TILE_SYNC();

    int vr = 0, vw = 2;

    // ---- periods 1..30 (two per iteration for S/K parity) ----
    for (int kp = 1; kp <= 29; kp += 2) {
        // period kp (odd): QK(kp)->S_b  ||  SMF+PV(kp-1) from S_a, mask mA
        LDMASK(kp, mB);                  // next period's mask, issued FIRST
        STAGE(kp + 1, 0, vw);
        QK(1, S_b0, S_b1, S_b2, S_b3);
        SMF(S_a0, S_a1, S_a2, S_a3, mA);
        PV(vr);
        TILE_SYNC();
        ROT3(vr); ROT3(vw);

        // period kp+1 (even): QK(kp+1)->S_a  ||  SMF+PV(kp) from S_b, mask mB
        LDMASK(kp + 1, mA);
        STAGE(kp + 2, 1, vw);
        QK(0, S_a0, S_a1, S_a2, S_a3);
        SMF(S_b0, S_b1, S_b2, S_b3, mB);
        PV(vr);
        TILE_SYNC();
        ROT3(vr); ROT3(vw);
    }

    // ---- period 31: QK(31)->S_b || SMF+PV(30) with mask mA(=30) ----
    LDMASK(31, mB);
    QK(1, S_b0, S_b1, S_b2, S_b3);
    SMF(S_a0, S_a1, S_a2, S_a3, mA);
    PV(vr);
    ROT3(vr);

    // ---- epilogue period: SMF+PV(31) with mask mB(=31) ----
    SMF(S_b0, S_b1, S_b2, S_b3, mB);
    PV(vr);

    // ---- reduce per-lane partials across the 4 k-groups ----
#pragma unroll
    for (int off = 16; off <= 32; off <<= 1) {
        lrun += __shfl_xor(lrun, off);
        la2  += __shfl_xor(la2,  off);
        lam  += __shfl_xor(lam,  off);
    }

    const float inv = 1.0f / lrun;

#pragma unroll
    for (int dt = 0; dt < 4; ++dt) {
        float4 o;
        o.x = acc[dt][0] * inv; o.y = acc[dt][1] * inv;
        o.z = acc[dt][2] * inv; o.w = acc[dt][3] * inv;
        *(float4*)(out + hoff + (size_t)qg * DIM + 16 * dt + 4 * lq) = o;
    }

    float part = la2 * inv * inv - 2.0f * lam * inv;
    part = (l < 16) ? part : 0.f;
#pragma unroll
    for (int off = 1; off <= 8; off <<= 1) part += __shfl_xor(part, off);
    if (l == 0) atomicAdd(loss, part);
}

// ============================================================================
// Fallback (proven r3 kernel) + standalone masksq if workspace too small.
// ============================================================================
__global__ void masksq_kernel(const float* __restrict__ Msk, float* __restrict__ loss)
{
    __shared__ float red[4];
    float s = 0.f;
    const size_t n4 = (size_t)LSEQ * LSEQ / 4;
    for (size_t i = (size_t)blockIdx.x * blockDim.x + threadIdx.x; i < n4;
         i += (size_t)gridDim.x * blockDim.x) {
        float4 v = ((const float4*)Msk)[i];
        s += v.x * v.x + v.y * v.y + v.z * v.z + v.w * v.w;
    }
#pragma unroll
    for (int off = 1; off <= 32; off <<= 1) s += __shfl_xor(s, off);
    if ((threadIdx.x & 63) == 0) red[threadIdx.x >> 6] = s;
    __syncthreads();
    if (threadIdx.x == 0) {
        float tot = red[0] + red[1] + red[2] + red[3];
        atomicAdd(loss, 32.0f * tot);
    }
}

__launch_bounds__(256, 4)
__global__ void attn_fallback_kernel(const float* __restrict__ Q,
                                     const float* __restrict__ K,
                                     const float* __restrict__ V,
                                     const float* __restrict__ Msk,
                                     float* __restrict__ out,
                                     float* __restrict__ loss)
{
    __shared__ __align__(16) u16 lds_k[64][72];
    __shared__ __align__(16) u16 lds_v[64][68];

    const int t  = threadIdx.x;
    const int wg   = ((int)blockIdx.x & 7) * 128 + ((int)blockIdx.x >> 3);
    const int head = wg >> 5;
    const int qb   = wg & 31;
    const int qbase = qb * QBLK;
    const int w  = t >> 6;
    const int l  = t & 63;
    const int lr = l & 15;
    const int lq = l >> 4;

    const size_t hoff = (size_t)head * LSEQ * DIM;
    const int qg = qbase + 16 * w + lr;

    bf16x8 qf[2];
#pragma unroll
    for (int s = 0; s < 2; ++s) {
        const float* src = Q + hoff + (size_t)qg * DIM + 32 * s + 8 * lq;
        float4 a = *(const float4*)(src);
        float4 b = *(const float4*)(src + 4);
        union { u16 h[8]; bf16x8 v; } u;
        u.h[0] = f2bf(a.x * QSCALE); u.h[1] = f2bf(a.y * QSCALE);
        u.h[2] = f2bf(a.z * QSCALE); u.h[3] = f2bf(a.w * QSCALE);
        u.h[4] = f2bf(b.x * QSCALE); u.h[5] = f2bf(b.y * QSCALE);
        u.h[6] = f2bf(b.z * QSCALE); u.h[7] = f2bf(b.w * QSCALE);
        qf[s] = u.v;
    }

    f32x4 acc[4];
#pragma unroll
    for (int dt = 0; dt < 4; ++dt) acc[dt] = (f32x4){0.f, 0.f, 0.f, 0.f};
    float mrun = -1e30f, lrun = 0.f, la2 = 0.f, lam = 0.f;

    for (int kb = 0; kb < NTILE; ++kb) {
        const int kbase = kb * KBLK;
        __syncthreads();
        f32x4 mreg[4];
        {
            const float* mp_ = Msk + (size_t)qg * LSEQ + kbase + 4 * lq;
#pragma unroll
            for (int m = 0; m < 4; ++m)
                mreg[m] = *(const f32x4*)(mp_ + 16 * m);
        }
        {
            const float* Kg = K + hoff + (size_t)kbase * DIM;
            const float* Vg = V + hoff + (size_t)kbase * DIM;
#pragma unroll
            for (int i = 0; i < 4; ++i) {
                const int id = t + 256 * i;
                const int r = id >> 4, c = (id & 15) * 4;
                float4 kv = *(const float4*)(Kg + r * DIM + c);
                float4 vv = *(const float4*)(Vg + r * DIM + c);
                st4bf(&lds_k[r][c], kv);
                lds_v[c + 0][r] = f2bf(vv.x);
                lds_v[c + 1][r] = f2bf(vv.y);
                lds_v[c + 2][r] = f2bf(vv.z);
                lds_v[c + 3][r] = f2bf(vv.w);
            }
        }
        __syncthreads();

        f32x4 S[4];
#pragma unroll
        for (int m = 0; m < 4; ++m) {
            bf16x8 kf0 = *(const bf16x8*)&lds_k[16 * m + lr][8 * lq];
            bf16x8 kf1 = *(const bf16x8*)&lds_k[16 * m + lr][32 + 8 * lq];
            f32x4 z = (f32x4){0.f, 0.f, 0.f, 0.f};
            z = __builtin_amdgcn_mfma_f32_16x16x32_bf16(kf0, qf[0], z, 0, 0, 0);
            z = __builtin_amdgcn_mfma_f32_16x16x32_bf16(kf1, qf[1], z, 0, 0, 0);
            S[m] = z;
        }

        float tm = fmaxf(fmaxf(fmaxf(S[0][0], S[0][1]), fmaxf(S[0][2], S[0][3])),
                         fmaxf(fmaxf(S[1][0], S[1][1]), fmaxf(S[1][2], S[1][3])));
        tm = fmaxf(tm, fmaxf(fmaxf(fmaxf(S[2][0], S[2][1]), fmaxf(S[2][2], S[2][3])),
                             fmaxf(fmaxf(S[3][0], S[3][1]), fmaxf(S[3][2], S[3][3]))));
        tm = fmaxf(tm, __shfl_xor(tm, 16));
        tm = fmaxf(tm, __shfl_xor(tm, 32));
        if (!__all(tm - mrun <= RESCALE_THR)) {
            const float mn = fmaxf(mrun, tm);
            const float al = __builtin_amdgcn_exp2f(mrun - mn);
            mrun = mn;
            lrun *= al; la2 *= al * al; lam *= al;
#pragma unroll
            for (int dt = 0; dt < 4; ++dt) acc[dt] *= al;
        }

        float psum = 0.f, pp2 = 0.f, ppm = 0.f;
        u16 pb[16];
#pragma unroll
        for (int m = 0; m < 4; ++m) {
#pragma unroll
            for (int r = 0; r < 4; ++r) {
                float p = __builtin_amdgcn_exp2f(S[m][r] - mrun);
                psum += p;
                pp2  += p * p;
                ppm  += p * mreg[m][r];
                pb[4 * m + r] = f2bf(p);
            }
        }
        lrun += psum; la2 += pp2; lam += ppm;

        bf16x8 pf[2];
#pragma unroll
        for (int mp = 0; mp < 2; ++mp) {
            union { u16 h[8]; bf16x8 v; } u;
#pragma unroll
            for (int j = 0; j < 4; ++j) { u.h[j] = pb[8 * mp + j]; u.h[4 + j] = pb[8 * mp + 4 + j]; }
            pf[mp] = u.v;
        }
#pragma unroll
        for (int dt = 0; dt < 4; ++dt) {
#pragma unroll
            for (int mp = 0; mp < 2; ++mp) {
                bf16x8 vf = comb64(&lds_v[16 * dt + lr][32 * mp + 4 * lq],
                                   &lds_v[16 * dt + lr][32 * mp + 16 + 4 * lq]);
                acc[dt] = __builtin_amdgcn_mfma_f32_16x16x32_bf16(vf, pf[mp], acc[dt], 0, 0, 0);
            }
        }
    }

#pragma unroll
    for (int off = 16; off <= 32; off <<= 1) {
        lrun += __shfl_xor(lrun, off);
        la2  += __shfl_xor(la2,  off);
        lam  += __shfl_xor(lam,  off);
    }
    const float inv = 1.0f / lrun;
#pragma unroll
    for (int dt = 0; dt < 4; ++dt) {
        float4 o;
        o.x = acc[dt][0] * inv; o.y = acc[dt][1] * inv;
        o.z = acc[dt][2] * inv; o.w = acc[dt][3] * inv;
        *(float4*)(out + hoff + (size_t)qg * DIM + 16 * dt + 4 * lq) = o;
    }
    float part = la2 * inv * inv - 2.0f * lam * inv;
    part = (l < 16) ? part : 0.f;
#pragma unroll
    for (int off = 1; off <= 8; off <<= 1) part += __shfl_xor(part, off);
    if (l == 0) atomicAdd(loss, part);
}

extern "C" void kernel_launch(void* const* d_in, const int* in_sizes, int n_in,
                              void* d_out, int out_size, void* d_ws, size_t ws_size,
                              hipStream_t stream)
{
    const float* Q   = (const float*)d_in[0];
    const float* K   = (const float*)d_in[1];
    const float* V   = (const float*)d_in[2];
    const float* Msk = (const float*)d_in[3];
    float* out  = (float*)d_out;
    float* loss = out + (size_t)NHEAD * LSEQ * DIM;  // element 4194304

    hipMemsetAsync(loss, 0, sizeof(float), stream);

    const size_t need = (size_t)2 * NHEAD * NTILE * 4096 * sizeof(u16);  // 16 MB
    if (d_ws && ws_size >= need) {
        u16* wsK = (u16*)d_ws;
        u16* wsV = wsK + (size_t)NHEAD * NTILE * 4096;
        prepack_kernel<<<NHEAD * NTILE, 256, 0, stream>>>(K, V, Msk, wsK, wsV, loss);
        attn_fused_kernel<<<NHEAD * (LSEQ / QBLK), 256, 0, stream>>>(Q, wsK, wsV, Msk, out, loss);
    } else {
        masksq_kernel<<<256, 256, 0, stream>>>(Msk, loss);
        attn_fallback_kernel<<<NHEAD * (LSEQ / QBLK), 256, 0, stream>>>(Q, K, V, Msk, out, loss);
    }
}

// Round 13
// 145.772 us; speedup vs baseline: 1.0553x; 1.0553x over previous
//
#include <hip/hip_runtime.h>

#define NHEAD 32
#define LSEQ  2048
#define DIM   64
#define QBLK  64
#define KBLK  64
#define NTILE (LSEQ / KBLK)

typedef float  f32x4  __attribute__((ext_vector_type(4)));
typedef __bf16 bf16x8 __attribute__((ext_vector_type(8)));
typedef unsigned short u16;

__device__ __forceinline__ u16 f2bf(float f) {
    return __builtin_bit_cast(u16, (__bf16)f);   // HW RNE convert
}
__device__ __forceinline__ void st4bf(u16* p, float4 v) {
    union { u16 h[4]; uint2 q; } pk;
    pk.h[0] = f2bf(v.x); pk.h[1] = f2bf(v.y);
    pk.h[2] = f2bf(v.z); pk.h[3] = f2bf(v.w);
    *(uint2*)p = pk.q;
}
__device__ __forceinline__ bf16x8 comb64(const u16* a, const u16* b) {
    union { uint2 q[2]; bf16x8 v; } u;
    u.q[0] = *(const uint2*)a;
    u.q[1] = *(const uint2*)b;
    return u.v;
}

// async global->LDS, 16B per lane (HW: wave-uniform LDS base + lane*16)
__device__ __forceinline__ void gl_lds16(const u16* g, u16* l) {
    __builtin_amdgcn_global_load_lds(
        (const __attribute__((address_space(1))) void*)g,
        (__attribute__((address_space(3))) void*)l, 16, 0, 0);
}

// drain own async stages + barrier (no lgkm drain: zero ds_writes in-loop;
// all ds_reads are consumed -> lgkm-waited before the barrier)
#define TILE_SYNC() asm volatile("s_waitcnt vmcnt(0)\n\ts_barrier" ::: "memory")

// 0.125 (1/sqrt(64)) * log2(e): softmax computed in exp2 domain
#define QSCALE 0.18033688011112042f
#define RESCALE_THR 8.0f

// ============================================================================
// Pre-pass: K -> bf16 tiles, V -> V^T bf16 tiles (gload_lds-linear + XOR-
// swizzled layout), PLUS the mask^2 loss term. (proven r4-r7)
// ============================================================================
__global__ void prepack_kernel(const float* __restrict__ K,
                               const float* __restrict__ V,
                               const float* __restrict__ Msk,
                               u16* __restrict__ wsK, u16* __restrict__ wsV,
                               float* __restrict__ loss)
{
    __shared__ float sv[64][65];
    __shared__ float red2[4];
    const int b = blockIdx.x;          // head*NTILE + kb
    const int head = b >> 5, kb = b & 31;
    const int t = threadIdx.x;
    const size_t hoff = (size_t)head * LSEQ * DIM;
    const float* Kg = K + hoff + (size_t)(kb * KBLK) * DIM;
    const float* Vg = V + hoff + (size_t)(kb * KBLK) * DIM;
    u16* outK = wsK + (size_t)b * 4096;
    u16* outV = wsV + (size_t)b * 4096;

#pragma unroll
    for (int i = 0; i < 16; ++i) {
        const int e = t + 256 * i;
        sv[e >> 6][e & 63] = Vg[e];
    }
#pragma unroll
    for (int i = 0; i < 2; ++i) {
        const int c = t + 256 * i;
        const int r = c >> 3, q = c & 7;
        const int d0 = 8 * (q ^ (r & 7));
        float4 a  = *(const float4*)(Kg + r * DIM + d0);
        float4 bb = *(const float4*)(Kg + r * DIM + d0 + 4);
        union { u16 h[8]; uint4 u; } pk;
        pk.h[0]=f2bf(a.x);  pk.h[1]=f2bf(a.y);  pk.h[2]=f2bf(a.z);  pk.h[3]=f2bf(a.w);
        pk.h[4]=f2bf(bb.x); pk.h[5]=f2bf(bb.y); pk.h[6]=f2bf(bb.z); pk.h[7]=f2bf(bb.w);
        *(uint4*)(outK + c * 8) = pk.u;
    }
    __syncthreads();
#pragma unroll
    for (int i = 0; i < 2; ++i) {
        const int c = t + 256 * i;
        const int d = c >> 3, q = c & 7;
        const int cl = q ^ (d & 7);
        const int mp = cl >> 2, lq = cl & 3;
        union { u16 h[8]; uint4 u; } pk;
#pragma unroll
        for (int s = 0; s < 2; ++s) {
            const int k0 = 4 * (8 * mp + 4 * s + lq);
#pragma unroll
            for (int j = 0; j < 4; ++j)
                pk.h[4 * s + j] = f2bf(sv[k0 + j][d]);
        }
        *(uint4*)(outV + c * 8) = pk.u;
    }

    float s = 0.f;
    const float4* mq = (const float4*)(Msk + (size_t)b * 4096);
#pragma unroll
    for (int i = 0; i < 4; ++i) {
        float4 v = mq[t + 256 * i];
        s += v.x * v.x + v.y * v.y + v.z * v.z + v.w * v.w;
    }
#pragma unroll
    for (int off = 1; off <= 32; off <<= 1) s += __shfl_xor(s, off);
    if ((t & 63) == 0) red2[t >> 6] = s;
    __syncthreads();
    if (t == 0)
        atomicAdd(loss, 32.0f * (red2[0] + red2[1] + red2[2] + red2[3]));
}

// ----------------------------------------------------------------------------
// Textual macros (rule #20: no lambda/pointer boundaries for register state).
// ----------------------------------------------------------------------------
#define STAGE(tile, kbuf, vbuf)                                                \
    {                                                                          \
        const u16* gk = srcK + (size_t)(tile) * 4096;                          \
        const u16* gv = srcV + (size_t)(tile) * 4096;                          \
        gl_lds16(gk,        &lds_k[kbuf][t * 8]);                              \
        gl_lds16(gk + 2048, &lds_k[kbuf][t * 8 + 2048]);                       \
        gl_lds16(gv,        &lds_v[vbuf][t * 8]);                              \
        gl_lds16(gv + 2048, &lds_v[vbuf][t * 8 + 2048]);                       \
    }

#define LDMASK(kb_)                                                            \
    {                                                                          \
        const float* mp_ = Msk + (size_t)qg * LSEQ + (kb_) * KBLK + 4 * lq;    \
        mM0 = *(const f32x4*)(mp_);                                            \
        mM1 = *(const f32x4*)(mp_ + 16);                                       \
        mM2 = *(const f32x4*)(mp_ + 32);                                       \
        mM3 = *(const f32x4*)(mp_ + 48);                                       \
    }

#define QK1(kb_, mm, Sdst)                                                     \
    {                                                                          \
        const u16* kro = (kb_) + (16 * (mm) + lr) * 64;                        \
        bf16x8 kf0 = *(const bf16x8*)(kro + ((lq ^ x7) << 3));                 \
        bf16x8 kf1 = *(const bf16x8*)(kro + (((lq + 4) ^ x7) << 3));           \
        f32x4 z = (f32x4){0.f, 0.f, 0.f, 0.f};                                 \
        z = __builtin_amdgcn_mfma_f32_16x16x32_bf16(kf0, qf[0], z, 0, 0, 0);   \
        z = __builtin_amdgcn_mfma_f32_16x16x32_bf16(kf1, qf[1], z, 0, 0, 0);   \
        Sdst = z;                                                              \
    }

// QK for tile -> 4 named S regs (independent of the SMF/PV chain below it)
#define QK(kbuf, SD0, SD1, SD2, SD3)                                           \
    {                                                                          \
        const u16* kb_ = &lds_k[kbuf][0];                                      \
        __builtin_amdgcn_s_setprio(1);                                         \
        QK1(kb_, 0, SD0) QK1(kb_, 1, SD1) QK1(kb_, 2, SD2) QK1(kb_, 3, SD3)    \
        __builtin_amdgcn_s_setprio(0);                                         \
    }

#define SMPART(Sm, Mm, base)                                                   \
    {                                                                          \
        _Pragma("unroll")                                                      \
        for (int r = 0; r < 4; ++r) {                                          \
            float pe = __builtin_amdgcn_exp2f(Sm[r] - mrun);                   \
            psum += pe;                                                        \
            pp2  += pe * pe;                                                   \
            ppm  += pe * Mm[r];                                                \
            pb[(base) + r] = f2bf(pe);                                         \
        }                                                                      \
    }

// softmax-finish of the PREVIOUS tile (VALU only) -> pf0/pf1 + running state
#define SMF(SS0, SS1, SS2, SS3)                                                \
    {                                                                          \
        float tm = fmaxf(fmaxf(fmaxf(SS0[0], SS0[1]), fmaxf(SS0[2], SS0[3])),  \
                         fmaxf(fmaxf(SS1[0], SS1[1]), fmaxf(SS1[2], SS1[3]))); \
        tm = fmaxf(tm, fmaxf(fmaxf(fmaxf(SS2[0], SS2[1]), fmaxf(SS2[2], SS2[3])), \
                             fmaxf(fmaxf(SS3[0], SS3[1]), fmaxf(SS3[2], SS3[3])))); \
        if (!__all(tm - mrun <= RESCALE_THR)) {                                \
            tm = fmaxf(tm, __shfl_xor(tm, 16));                                \
            tm = fmaxf(tm, __shfl_xor(tm, 32));                                \
            const float mn = fmaxf(mrun, tm);                                  \
            const float al = __builtin_amdgcn_exp2f(mrun - mn);                \
            mrun = mn;                                                         \
            lrun *= al; la2 *= al * al; lam *= al;                             \
            _Pragma("unroll")                                                  \
            for (int dt = 0; dt < 4; ++dt) acc[dt] *= al;                      \
        }                                                                      \
        float psum = 0.f, pp2 = 0.f, ppm = 0.f;                                \
        u16 pb[16];                                                            \
        SMPART(SS0, mM0, 0) SMPART(SS1, mM1, 4)                                \
        SMPART(SS2, mM2, 8) SMPART(SS3, mM3, 12)                               \
        lrun += psum; la2 += pp2; lam += ppm;                                  \
        {                                                                      \
            union { u16 h[8]; bf16x8 v; } u;                                   \
            u.h[0] = pb[0]; u.h[1] = pb[1]; u.h[2] = pb[2]; u.h[3] = pb[3];    \
            u.h[4] = pb[4]; u.h[5] = pb[5]; u.h[6] = pb[6]; u.h[7] = pb[7];    \
            pf0 = u.v;                                                         \
        }                                                                      \
        {                                                                      \
            union { u16 h[8]; bf16x8 v; } u;                                   \
            u.h[0] = pb[8];  u.h[1] = pb[9];  u.h[2] = pb[10]; u.h[3] = pb[11];\
            u.h[4] = pb[12]; u.h[5] = pb[13]; u.h[6] = pb[14]; u.h[7] = pb[15];\
            pf1 = u.v;                                                         \
        }                                                                      \
    }

// PV accumulate of the PREVIOUS tile from V buffer vidx (uses pf0/pf1)
#define PV(vidx)                                                               \
    {                                                                          \
        const u16* vb_ = &lds_v[vidx][0];                                      \
        __builtin_amdgcn_s_setprio(1);                                         \
        _Pragma("unroll")                                                      \
        for (int dt = 0; dt < 4; ++dt) {                                       \
            const u16* vro = vb_ + (16 * dt + lr) * 64;                        \
            bf16x8 vfa = *(const bf16x8*)(vro + ((lq ^ x7) << 3));             \
            bf16x8 vfb = *(const bf16x8*)(vro + (((4 + lq) ^ x7) << 3));       \
            acc[dt] = __builtin_amdgcn_mfma_f32_16x16x32_bf16(vfa, pf0, acc[dt], 0, 0, 0); \
            acc[dt] = __builtin_amdgcn_mfma_f32_16x16x32_bf16(vfb, pf1, acc[dt], 0, 0, 0); \
        }                                                                      \
        __builtin_amdgcn_s_setprio(0);                                         \
    }

#define ROT3(x) x = ((x) == 2) ? 0 : ((x) + 1);

// ============================================================================
// Main fused kernel: two-tile software pipeline (best measured configuration,
// round 7: 131us attn / 146us total). Per period p the wave runs TWO
// independent chains: QK(p) [LDS+MFMA] and SMF(p-1)+PV(p-1) [VALU+MFMA].
// K double-buffered, V TRIPLE-buffered (live tiles p-1/p/p+1), one barrier
// per period. Mask load hides behind QK. Single mask set (mM*): r12 measured
// that double-buffering it across TILE_SYNC spills (+20MB scratch, +9us).
// ============================================================================
__launch_bounds__(256, 4)
__global__ void attn_fused_kernel(const float* __restrict__ Q,
                                  const u16* __restrict__ wsK,
                                  const u16* __restrict__ wsV,
                                  const float* __restrict__ Msk,
                                  float* __restrict__ out,
                                  float* __restrict__ loss)
{
    __shared__ __align__(16) u16 lds_k[2][4096];   // 8KB K tile image x2
    __shared__ __align__(16) u16 lds_v[3][4096];   // 8KB V^T tile image x3

    const int t  = threadIdx.x;
    // bijective XCD-chunked swizzle: 1024 blocks, 8 XCDs, 128-block chunks
    const int wg   = ((int)blockIdx.x & 7) * 128 + ((int)blockIdx.x >> 3);
    const int head = wg >> 5;
    const int qb   = wg & 31;
    const int qbase = qb * QBLK;
    const int w  = t >> 6;
    const int l  = t & 63;
    const int lr = l & 15;
    const int lq = l >> 4;
    const int x7 = lr & 7;

    const size_t hoff = (size_t)head * LSEQ * DIM;
    const int qg = qbase + 16 * w + lr;

    // ---- Q fragments, scale folded in (slots c = 32s + 8lq + j) ----
    bf16x8 qf[2];
#pragma unroll
    for (int s = 0; s < 2; ++s) {
        const float* src = Q + hoff + (size_t)qg * DIM + 32 * s + 8 * lq;
        float4 a = *(const float4*)(src);
        float4 b = *(const float4*)(src + 4);
        union { u16 h[8]; bf16x8 v; } u;
        u.h[0] = f2bf(a.x * QSCALE); u.h[1] = f2bf(a.y * QSCALE);
        u.h[2] = f2bf(a.z * QSCALE); u.h[3] = f2bf(a.w * QSCALE);
        u.h[4] = f2bf(b.x * QSCALE); u.h[5] = f2bf(b.y * QSCALE);
        u.h[6] = f2bf(b.z * QSCALE); u.h[7] = f2bf(b.w * QSCALE);
        qf[s] = u.v;
    }

    f32x4 acc[4];
#pragma unroll
    for (int dt = 0; dt < 4; ++dt) acc[dt] = (f32x4){0.f, 0.f, 0.f, 0.f};
    float mrun = -1e30f, lrun = 0.f, la2 = 0.f, lam = 0.f;

    const u16* srcK = wsK + (size_t)(head * NTILE) * 4096 + t * 8;
    const u16* srcV = wsV + (size_t)(head * NTILE) * 4096 + t * 8;

    // pipeline register state: named, spill-proof
    f32x4 S_a0, S_a1, S_a2, S_a3, S_b0, S_b1, S_b2, S_b3;
    f32x4 mM0, mM1, mM2, mM3;
    bf16x8 pf0, pf1;

    // ---- prologue: tile 0 staged+synced, QK(0), tile 1 staged+synced ----
    STAGE(0, 0, 0);
    TILE_SYNC();
    STAGE(1, 1, 1);
    QK(0, S_a0, S_a1, S_a2, S_a3);       // tile 0 scores -> S_a
    TILE_SYNC();

    int vr = 0, vw = 2;

    // ---- periods 1..30 (two per iteration for S/K parity) ----
    for (int kp = 1; kp <= 29; kp += 2) {
        // period kp (odd): QK(kp)->S_b  ||  SMF+PV(kp-1) from S_a
        STAGE(kp + 1, 0, vw);
        LDMASK(kp - 1);                  // consumed in SMF below, hides behind QK
        QK(1, S_b0, S_b1, S_b2, S_b3);
        SMF(S_a0, S_a1, S_a2, S_a3);
        PV(vr);
        TILE_SYNC();
        ROT3(vr); ROT3(vw);

        // period kp+1 (even): QK(kp+1)->S_a  ||  SMF+PV(kp) from S_b
        STAGE(kp + 2, 1, vw);
        LDMASK(kp);
        QK(0, S_a0, S_a1, S_a2, S_a3);
        SMF(S_b0, S_b1, S_b2, S_b3);
        PV(vr);
        TILE_SYNC();
        ROT3(vr); ROT3(vw);
    }

    // ---- period 31: QK(31)->S_b || SMF+PV(30); no further staging ----
    LDMASK(30);
    QK(1, S_b0, S_b1, S_b2, S_b3);
    SMF(S_a0, S_a1, S_a2, S_a3);
    PV(vr);
    ROT3(vr);

    // ---- epilogue period: SMF+PV(31) ----
    LDMASK(31);
    SMF(S_b0, S_b1, S_b2, S_b3);
    PV(vr);

    // ---- reduce per-lane partials across the 4 k-groups ----
#pragma unroll
    for (int off = 16; off <= 32; off <<= 1) {
        lrun += __shfl_xor(lrun, off);
        la2  += __shfl_xor(la2,  off);
        lam  += __shfl_xor(lam,  off);
    }

    const float inv = 1.0f / lrun;

#pragma unroll
    for (int dt = 0; dt < 4; ++dt) {
        float4 o;
        o.x = acc[dt][0] * inv; o.y = acc[dt][1] * inv;
        o.z = acc[dt][2] * inv; o.w = acc[dt][3] * inv;
        *(float4*)(out + hoff + (size_t)qg * DIM + 16 * dt + 4 * lq) = o;
    }

    float part = la2 * inv * inv - 2.0f * lam * inv;
    part = (l < 16) ? part : 0.f;
#pragma unroll
    for (int off = 1; off <= 8; off <<= 1) part += __shfl_xor(part, off);
    if (l == 0) atomicAdd(loss, part);
}

// ============================================================================
// Fallback (proven r3 kernel) + standalone masksq if workspace too small.
// ============================================================================
__global__ void masksq_kernel(const float* __restrict__ Msk, float* __restrict__ loss)
{
    __shared__ float red[4];
    float s = 0.f;
    const size_t n4 = (size_t)LSEQ * LSEQ / 4;
    for (size_t i = (size_t)blockIdx.x * blockDim.x + threadIdx.x; i < n4;
         i += (size_t)gridDim.x * blockDim.x) {
        float4 v = ((const float4*)Msk)[i];
        s += v.x * v.x + v.y * v.y + v.z * v.z + v.w * v.w;
    }
#pragma unroll
    for (int off = 1; off <= 32; off <<= 1) s += __shfl_xor(s, off);
    if ((threadIdx.x & 63) == 0) red[threadIdx.x >> 6] = s;
    __syncthreads();
    if (threadIdx.x == 0) {
        float tot = red[0] + red[1] + red[2] + red[3];
        atomicAdd(loss, 32.0f * tot);
    }
}

__launch_bounds__(256, 4)
__global__ void attn_fallback_kernel(const float* __restrict__ Q,
                                     const float* __restrict__ K,
                                     const float* __restrict__ V,
                                     const float* __restrict__ Msk,
                                     float* __restrict__ out,
                                     float* __restrict__ loss)
{
    __shared__ __align__(16) u16 lds_k[64][72];
    __shared__ __align__(16) u16 lds_v[64][68];

    const int t  = threadIdx.x;
    const int wg   = ((int)blockIdx.x & 7) * 128 + ((int)blockIdx.x >> 3);
    const int head = wg >> 5;
    const int qb   = wg & 31;
    const int qbase = qb * QBLK;
    const int w  = t >> 6;
    const int l  = t & 63;
    const int lr = l & 15;
    const int lq = l >> 4;

    const size_t hoff = (size_t)head * LSEQ * DIM;
    const int qg = qbase + 16 * w + lr;

    bf16x8 qf[2];
#pragma unroll
    for (int s = 0; s < 2; ++s) {
        const float* src = Q + hoff + (size_t)qg * DIM + 32 * s + 8 * lq;
        float4 a = *(const float4*)(src);
        float4 b = *(const float4*)(src + 4);
        union { u16 h[8]; bf16x8 v; } u;
        u.h[0] = f2bf(a.x * QSCALE); u.h[1] = f2bf(a.y * QSCALE);
        u.h[2] = f2bf(a.z * QSCALE); u.h[3] = f2bf(a.w * QSCALE);
        u.h[4] = f2bf(b.x * QSCALE); u.h[5] = f2bf(b.y * QSCALE);
        u.h[6] = f2bf(b.z * QSCALE); u.h[7] = f2bf(b.w * QSCALE);
        qf[s] = u.v;
    }

    f32x4 acc[4];
#pragma unroll
    for (int dt = 0; dt < 4; ++dt) acc[dt] = (f32x4){0.f, 0.f, 0.f, 0.f};
    float mrun = -1e30f, lrun = 0.f, la2 = 0.f, lam = 0.f;

    for (int kb = 0; kb < NTILE; ++kb) {
        const int kbase = kb * KBLK;
        __syncthreads();
        f32x4 mreg[4];
        {
            const float* mp_ = Msk + (size_t)qg * LSEQ + kbase + 4 * lq;
#pragma unroll
            for (int m = 0; m < 4; ++m)
                mreg[m] = *(const f32x4*)(mp_ + 16 * m);
        }
        {
            const float* Kg = K + hoff + (size_t)kbase * DIM;
            const float* Vg = V + hoff + (size_t)kbase * DIM;
#pragma unroll
            for (int i = 0; i < 4; ++i) {
                const int id = t + 256 * i;
                const int r = id >> 4, c = (id & 15) * 4;
                float4 kv = *(const float4*)(Kg + r * DIM + c);
                float4 vv = *(const float4*)(Vg + r * DIM + c);
                st4bf(&lds_k[r][c], kv);
                lds_v[c + 0][r] = f2bf(vv.x);
                lds_v[c + 1][r] = f2bf(vv.y);
                lds_v[c + 2][r] = f2bf(vv.z);
                lds_v[c + 3][r] = f2bf(vv.w);
            }
        }
        __syncthreads();

        f32x4 S[4];
#pragma unroll
        for (int m = 0; m < 4; ++m) {
            bf16x8 kf0 = *(const bf16x8*)&lds_k[16 * m + lr][8 * lq];
            bf16x8 kf1 = *(const bf16x8*)&lds_k[16 * m + lr][32 + 8 * lq];
            f32x4 z = (f32x4){0.f, 0.f, 0.f, 0.f};
            z = __builtin_amdgcn_mfma_f32_16x16x32_bf16(kf0, qf[0], z, 0, 0, 0);
            z = __builtin_amdgcn_mfma_f32_16x16x32_bf16(kf1, qf[1], z, 0, 0, 0);
            S[m] = z;
        }

        float tm = fmaxf(fmaxf(fmaxf(S[0][0], S[0][1]), fmaxf(S[0][2], S[0][3])),
                         fmaxf(fmaxf(S[1][0], S[1][1]), fmaxf(S[1][2], S[1][3])));
        tm = fmaxf(tm, fmaxf(fmaxf(fmaxf(S[2][0], S[2][1]), fmaxf(S[2][2], S[2][3])),
                             fmaxf(fmaxf(S[3][0], S[3][1]), fmaxf(S[3][2], S[3][3]))));
        tm = fmaxf(tm, __shfl_xor(tm, 16));
        tm = fmaxf(tm, __shfl_xor(tm, 32));
        if (!__all(tm - mrun <= RESCALE_THR)) {
            const float mn = fmaxf(mrun, tm);
            const float al = __builtin_amdgcn_exp2f(mrun - mn);
            mrun = mn;
            lrun *= al; la2 *= al * al; lam *= al;
#pragma unroll
            for (int dt = 0; dt < 4; ++dt) acc[dt] *= al;
        }

        float psum = 0.f, pp2 = 0.f, ppm = 0.f;
        u16 pb[16];
#pragma unroll
        for (int m = 0; m < 4; ++m) {
#pragma unroll
            for (int r = 0; r < 4; ++r) {
                float p = __builtin_amdgcn_exp2f(S[m][r] - mrun);
                psum += p;
                pp2  += p * p;
                ppm  += p * mreg[m][r];
                pb[4 * m + r] = f2bf(p);
            }
        }
        lrun += psum; la2 += pp2; lam += ppm;

        bf16x8 pf[2];
#pragma unroll
        for (int mp = 0; mp < 2; ++mp) {
            union { u16 h[8]; bf16x8 v; } u;
#pragma unroll
            for (int j = 0; j < 4; ++j) { u.h[j] = pb[8 * mp + j]; u.h[4 + j] = pb[8 * mp + 4 + j]; }
            pf[mp] = u.v;
        }
#pragma unroll
        for (int dt = 0; dt < 4; ++dt) {
#pragma unroll
            for (int mp = 0; mp < 2; ++mp) {
                bf16x8 vf = comb64(&lds_v[16 * dt + lr][32 * mp + 4 * lq],
                                   &lds_v[16 * dt + lr][32 * mp + 16 + 4 * lq]);
                acc[dt] = __builtin_amdgcn_mfma_f32_16x16x32_bf16(vf, pf[mp], acc[dt], 0, 0, 0);
            }
        }
    }

#pragma unroll
    for (int off = 16; off <= 32; off <<= 1) {
        lrun += __shfl_xor(lrun, off);
        la2  += __shfl_xor(la2,  off);
        lam  += __shfl_xor(lam,  off);
    }
    const float inv = 1.0f / lrun;
#pragma unroll
    for (int dt = 0; dt < 4; ++dt) {
        float4 o;
        o.x = acc[dt][0] * inv; o.y = acc[dt][1] * inv;
        o.z = acc[dt][2] * inv; o.w = acc[dt][3] * inv;
        *(float4*)(out + hoff + (size_t)qg * DIM + 16 * dt + 4 * lq) = o;
    }
    float part = la2 * inv * inv - 2.0f * lam * inv;
    part = (l < 16) ? part : 0.f;
#pragma unroll
    for (int off = 1; off <= 8; off <<= 1) part += __shfl_xor(part, off);
    if (l == 0) atomicAdd(loss, part);
}

extern "C" void kernel_launch(void* const* d_in, const int* in_sizes, int n_in,
                              void* d_out, int out_size, void* d_ws, size_t ws_size,
                              hipStream_t stream)
{
    const float* Q   = (const float*)d_in[0];
    const float* K   = (const float*)d_in[1];
    const float* V   = (const float*)d_in[2];
    const float* Msk = (const float*)d_in[3];
    float* out  = (float*)d_out;
    float* loss = out + (size_t)NHEAD * LSEQ * DIM;  // element 4194304

    hipMemsetAsync(loss, 0, sizeof(float), stream);

    const size_t need = (size_t)2 * NHEAD * NTILE * 4096 * sizeof(u16);  // 16 MB
    if (d_ws && ws_size >= need) {
        u16* wsK = (u16*)d_ws;
        u16* wsV = wsK + (size_t)NHEAD * NTILE * 4096;
        prepack_kernel<<<NHEAD * NTILE, 256, 0, stream>>>(K, V, Msk, wsK, wsV, loss);
        attn_fused_kernel<<<NHEAD * (LSEQ / QBLK), 256, 0, stream>>>(Q, wsK, wsV, Msk, out, loss);
    } else {
        masksq_kernel<<<256, 256, 0, stream>>>(Msk, loss);
        attn_fallback_kernel<<<NHEAD * (LSEQ / QBLK), 256, 0, stream>>>(Q, K, V, Msk, out, loss);
    }
}